// Round 1
// baseline (4490.844 us; speedup 1.0000x reference)
//
#include <hip/hip_runtime.h>
#include <math.h>

// Problem constants
constexpr int BN = 16;    // batch
constexpr int TN = 4096;  // sequence
constexpr int CN = 32;    // embed
constexpr int HN = 64;    // head size
constexpr int KT = 64;    // key tile

// ---------------------------------------------------------------------------
// Kernel 1: fused QKV projection.  One thread per (b,t) row.
// Weights staged in LDS (3 x 32x64 f32 = 24 KB), broadcast reads.
// ---------------------------------------------------------------------------
__global__ __launch_bounds__(256) void qkv_proj(
    const float* __restrict__ x,
    const float* __restrict__ Wk,
    const float* __restrict__ Wq,
    const float* __restrict__ Wv,
    float* __restrict__ qp,
    float* __restrict__ kp,
    float* __restrict__ vp)
{
    __shared__ float sWq[CN * HN];
    __shared__ float sWk[CN * HN];
    __shared__ float sWv[CN * HN];

    const int tid = threadIdx.x;
    for (int i = tid; i < CN * HN; i += 256) {
        sWq[i] = Wq[i];
        sWk[i] = Wk[i];
        sWv[i] = Wv[i];
    }
    __syncthreads();

    const long row = (long)blockIdx.x * 256 + tid;   // 0 .. B*T-1
    const float* xr = x + row * CN;

    float xv[CN];
#pragma unroll
    for (int c = 0; c < CN; c += 4) {
        float4 t4 = *reinterpret_cast<const float4*>(xr + c);
        xv[c + 0] = t4.x; xv[c + 1] = t4.y; xv[c + 2] = t4.z; xv[c + 3] = t4.w;
    }

    float* qo = qp + row * HN;
    float* ko = kp + row * HN;
    float* vo = vp + row * HN;

#pragma unroll 4
    for (int h = 0; h < HN; ++h) {
        float aq = 0.f, ak = 0.f, av = 0.f;
#pragma unroll
        for (int c = 0; c < CN; ++c) {
            const float xc = xv[c];
            aq += xc * sWq[c * HN + h];
            ak += xc * sWk[c * HN + h];
            av += xc * sWv[c * HN + h];
        }
        qo[h] = aq;
        ko[h] = ak;
        vo[h] = av;
    }
}

// ---------------------------------------------------------------------------
// Kernel 2: causal flash attention, f32.  One thread per query row.
// Block = 256 threads = 256 consecutive query rows of one batch.
// K/V tiles (64x64 f32 each) staged in LDS; per-(k,d) reads are
// wave-uniform -> LDS broadcast (no bank conflicts).
// All register arrays fully unrolled (compile-time indices only).
// ---------------------------------------------------------------------------
__global__ __launch_bounds__(256, 1) void attn(
    const float* __restrict__ qp,
    const float* __restrict__ kp,
    const float* __restrict__ vp,
    float* __restrict__ out)
{
    __shared__ float Ks[KT][HN];
    __shared__ float Vs[KT][HN];

    const int tid   = threadIdx.x;
    const int b     = blockIdx.y;
    const int qbase = blockIdx.x * 256;
    const int q     = qbase + tid;

    const float scale = 0.125f;   // 1/sqrt(64)

    // load this thread's q row into registers
    const float* qrow = qp + ((long)b * TN + q) * HN;
    float qv[HN];
#pragma unroll
    for (int d = 0; d < HN; d += 4) {
        float4 t4 = *reinterpret_cast<const float4*>(qrow + d);
        qv[d + 0] = t4.x; qv[d + 1] = t4.y; qv[d + 2] = t4.z; qv[d + 3] = t4.w;
    }

    float acc[HN];
#pragma unroll
    for (int d = 0; d < HN; ++d) acc[d] = 0.f;
    float m = -INFINITY;
    float l = 0.f;

    const int qmaxb  = qbase + 255;
    const int ntiles = qmaxb / KT + 1;

    const float* Kg_base = kp + (long)b * TN * HN;
    const float* Vg_base = vp + (long)b * TN * HN;

    for (int t = 0; t < ntiles; ++t) {
        const int kbase = t * KT;

        __syncthreads();   // previous tile's compute done before overwrite
        {
            const float4* Kg = reinterpret_cast<const float4*>(Kg_base + (long)kbase * HN);
            const float4* Vg = reinterpret_cast<const float4*>(Vg_base + (long)kbase * HN);
            float4* Ks4 = reinterpret_cast<float4*>(&Ks[0][0]);
            float4* Vs4 = reinterpret_cast<float4*>(&Vs[0][0]);
#pragma unroll
            for (int i = 0; i < (KT * HN / 4) / 256; ++i) {
                const int idx = i * 256 + tid;
                Ks4[idx] = Kg[idx];
                Vs4[idx] = Vg[idx];
            }
        }
        __syncthreads();

        // ---- scores for this tile ----
        const int klim = q - kbase;   // local key index must be <= klim
        float sv[KT];
#pragma unroll
        for (int k = 0; k < KT; ++k) {
            const float4* Kr = reinterpret_cast<const float4*>(&Ks[k][0]);
            float s0 = 0.f, s1 = 0.f, s2 = 0.f, s3 = 0.f;
#pragma unroll
            for (int d4 = 0; d4 < HN / 4; ++d4) {
                float4 kv = Kr[d4];
                s0 += qv[4 * d4 + 0] * kv.x;
                s1 += qv[4 * d4 + 1] * kv.y;
                s2 += qv[4 * d4 + 2] * kv.z;
                s3 += qv[4 * d4 + 3] * kv.w;
            }
            const float s = (s0 + s1) + (s2 + s3);
            sv[k] = (k <= klim) ? s * scale : -INFINITY;
        }

        // ---- online softmax update ----
        float tmax = -INFINITY;
#pragma unroll
        for (int k = 0; k < KT; ++k) tmax = fmaxf(tmax, sv[k]);
        const float mnew = fmaxf(m, tmax);      // finite after tile 0
        const float corr = __expf(m - mnew);    // exp(-inf - finite) = 0 on tile 0
        l *= corr;
#pragma unroll
        for (int d = 0; d < HN; ++d) acc[d] *= corr;

#pragma unroll
        for (int k = 0; k < KT; ++k) {
            const float p = __expf(sv[k] - mnew);   // 0 for masked keys
            l += p;
            const float4* Vr = reinterpret_cast<const float4*>(&Vs[k][0]);
#pragma unroll
            for (int d4 = 0; d4 < HN / 4; ++d4) {
                float4 vv = Vr[d4];
                acc[4 * d4 + 0] += p * vv.x;
                acc[4 * d4 + 1] += p * vv.y;
                acc[4 * d4 + 2] += p * vv.z;
                acc[4 * d4 + 3] += p * vv.w;
            }
        }
        m = mnew;
    }

    const float inv = 1.0f / l;
    float* orow = out + ((long)b * TN + q) * HN;
#pragma unroll
    for (int d = 0; d < HN; d += 4) {
        float4 t4;
        t4.x = acc[d + 0] * inv;
        t4.y = acc[d + 1] * inv;
        t4.z = acc[d + 2] * inv;
        t4.w = acc[d + 3] * inv;
        *reinterpret_cast<float4*>(orow + d) = t4;
    }
}

// ---------------------------------------------------------------------------
extern "C" void kernel_launch(void* const* d_in, const int* in_sizes, int n_in,
                              void* d_out, int out_size, void* d_ws, size_t ws_size,
                              hipStream_t stream) {
    const float* x  = (const float*)d_in[0];
    const float* Wk = (const float*)d_in[1];
    const float* Wq = (const float*)d_in[2];
    const float* Wv = (const float*)d_in[3];
    float* out = (float*)d_out;

    // ws layout: q | k | v, each B*T*H f32 (16.78 MB) -> 50.3 MB total
    float* qp = (float*)d_ws;
    float* kp = qp + (size_t)BN * TN * HN;
    float* vp = kp + (size_t)BN * TN * HN;

    // one thread per (b,t) row: B*T = 65536 rows = 256 blocks x 256 threads
    qkv_proj<<<dim3(256), dim3(256), 0, stream>>>(x, Wk, Wq, Wv, qp, kp, vp);

    // one thread per query row; block covers 256 rows of one batch
    attn<<<dim3(TN / 256, BN), dim3(256), 0, stream>>>(qp, kp, vp, out);
}

// Round 2
// 206.006 us; speedup vs baseline: 21.7995x; 21.7995x over previous
//
#include <hip/hip_runtime.h>
#include <hip/hip_bf16.h>
#include <math.h>

typedef short short8 __attribute__((ext_vector_type(8)));
typedef float f32x4 __attribute__((ext_vector_type(4)));
typedef unsigned short u16;

constexpr int TN = 4096;   // sequence
constexpr int CN = 32;     // embed
constexpr int HN = 64;     // head size
constexpr int QT = 128;    // q rows per block (4 waves x 32)
constexpr int KT = 64;     // keys per tile
constexpr int NQ = TN / QT; // 32 q-tiles per batch

__device__ __forceinline__ u16 f2bf(float f) {
    return __builtin_bit_cast(u16, __float2bfloat16(f));
}

// ---------------------------------------------------------------------------
// Kernel 1: fused QKV projection -> bf16.
// q, k row-major [b*t][64]; v TRANSPOSED per batch: vt[b][d][t] so the
// attention kernel can stage V^T tiles with linear swizzled copies.
// ---------------------------------------------------------------------------
__global__ __launch_bounds__(256) void qkv_proj(
    const float* __restrict__ x,
    const float* __restrict__ Wk,
    const float* __restrict__ Wq,
    const float* __restrict__ Wv,
    u16* __restrict__ qb, u16* __restrict__ kb, u16* __restrict__ vtb)
{
    __shared__ float sW[3][CN * HN];   // 0=q, 1=k, 2=v

    const int tid = threadIdx.x;
    for (int i = tid; i < CN * HN; i += 256) {
        sW[0][i] = Wq[i];
        sW[1][i] = Wk[i];
        sW[2][i] = Wv[i];
    }
    __syncthreads();

    const int row  = blockIdx.x * 256 + tid;   // 0 .. B*T-1
    const int b    = row >> 12;                // T = 4096
    const int tloc = row & (TN - 1);
    const float* xr = x + (size_t)row * CN;

    float xv[CN];
#pragma unroll
    for (int c = 0; c < CN; c += 4) {
        float4 t4 = *reinterpret_cast<const float4*>(xr + c);
        xv[c] = t4.x; xv[c + 1] = t4.y; xv[c + 2] = t4.z; xv[c + 3] = t4.w;
    }

    u16* qo = qb + (size_t)row * HN;
    u16* ko = kb + (size_t)row * HN;

#pragma unroll
    for (int h0 = 0; h0 < HN; h0 += 8) {
        float aq[8], ak[8], av[8];
#pragma unroll
        for (int j = 0; j < 8; ++j) { aq[j] = 0.f; ak[j] = 0.f; av[j] = 0.f; }

#pragma unroll
        for (int c = 0; c < CN; ++c) {
            const float xc = xv[c];
            const f32x4* wq = reinterpret_cast<const f32x4*>(&sW[0][c * HN + h0]);
            const f32x4* wk = reinterpret_cast<const f32x4*>(&sW[1][c * HN + h0]);
            const f32x4* wv = reinterpret_cast<const f32x4*>(&sW[2][c * HN + h0]);
#pragma unroll
            for (int j = 0; j < 4; ++j) {
                aq[j] += xc * wq[0][j];  aq[j + 4] += xc * wq[1][j];
                ak[j] += xc * wk[0][j];  ak[j + 4] += xc * wk[1][j];
                av[j] += xc * wv[0][j];  av[j + 4] += xc * wv[1][j];
            }
        }

        short8 pq, pk;
#pragma unroll
        for (int j = 0; j < 8; ++j) {
            pq[j] = (short)f2bf(aq[j]);
            pk[j] = (short)f2bf(ak[j]);
        }
        *reinterpret_cast<short8*>(qo + h0) = pq;
        *reinterpret_cast<short8*>(ko + h0) = pk;

        // transposed v store: vt[b][h][t]; lanes are consecutive tloc ->
        // each scalar store instruction writes 128B contiguous (coalesced)
#pragma unroll
        for (int j = 0; j < 8; ++j) {
            vtb[((size_t)b * HN + h0 + j) * TN + tloc] = f2bf(av[j]);
        }
    }
}

// ---------------------------------------------------------------------------
// Kernel 2: causal flash attention with bf16 MFMA (16x16x32).
// Block: 256 threads = 4 waves; wave w owns q rows [wq, wq+31] (2 M-frags).
// K tile [64 keys][64 d] and V^T tile [64 d][64 keys] staged in LDS with
// XOR swizzle  elem ^= (row&7)<<3  -> all b128 accesses conflict-free.
// P goes through per-wave LDS (bf16) to re-layout MFMA C/D -> A fragments.
// C/D layout (m89): D[row=(l>>4)*4+reg][col=l&15].
// ---------------------------------------------------------------------------
__global__ __launch_bounds__(256, 2) void attn_mfma(
    const u16* __restrict__ qb,
    const u16* __restrict__ kb,
    const u16* __restrict__ vtb,
    float* __restrict__ out)
{
    __shared__ u16 Ks[KT * HN];        // [key][d ^ swz]
    __shared__ u16 Vt[HN * KT];        // [d][k ^ swz]
    __shared__ u16 Ps[4][32 * KT];     // per wave: [q'][k ^ swz]

    const int tid  = threadIdx.x;
    const int lane = tid & 63;
    const int w    = tid >> 6;
    const int g    = lane >> 4;        // lane group 0..3
    const int c    = lane & 15;
    const int b    = blockIdx.y;
    // heavy-first + heavy/light pairing across the two dispatch rounds
    const int qt    = (blockIdx.y < 8) ? (NQ - 1 - (int)blockIdx.x) : (int)blockIdx.x;
    const int qbase = qt * QT;
    const int wq    = qbase + w * 32;  // wave's first q row

    const u16* Qg = qb  + (size_t)b * TN * HN;
    const u16* Kg = kb  + (size_t)b * TN * HN;
    const u16* Vg = vtb + (size_t)b * HN * TN;

    // hoisted Q A-fragments: [m2][kk]; lane holds Q[wq+m2*16+c][kk*32+g*8 ..+7]
    short8 qa[2][2];
#pragma unroll
    for (int m2 = 0; m2 < 2; ++m2)
#pragma unroll
        for (int kk = 0; kk < 2; ++kk)
            qa[m2][kk] = *reinterpret_cast<const short8*>(
                Qg + (size_t)(wq + m2 * 16 + c) * HN + kk * 32 + g * 8);

    f32x4 o[2][4];                     // [m2][dn], D rows = q, cols = d
    float m_[2][4], l_[2][4];
#pragma unroll
    for (int m2 = 0; m2 < 2; ++m2) {
#pragma unroll
        for (int n = 0; n < 4; ++n) { o[m2][n] = (f32x4){0.f, 0.f, 0.f, 0.f}; }
#pragma unroll
        for (int r = 0; r < 4; ++r) { m_[m2][r] = -INFINITY; l_[m2][r] = 0.f; }
    }

    const int ntiles = 2 * qt + 2;
    for (int t = 0; t < ntiles; ++t) {
        const int kbase = t * KT;

        __syncthreads();   // everyone done reading previous tile
        // ---- stage K and V^T tiles (swizzled, conflict-free b128) ----
#pragma unroll
        for (int i = 0; i < 2; ++i) {
            const int ci = tid + (i << 8);
            const int r  = ci >> 3;             // K: key row / Vt: d row
            const int e0 = (ci & 7) << 3;       // K: d0     / Vt: k0
            const int sw = e0 ^ ((r & 7) << 3);
            *reinterpret_cast<short8*>(&Ks[(r << 6) + sw]) =
                *reinterpret_cast<const short8*>(Kg + (size_t)(kbase + r) * HN + e0);
            *reinterpret_cast<short8*>(&Vt[(r << 6) + sw]) =
                *reinterpret_cast<const short8*>(Vg + (size_t)r * TN + kbase + e0);
        }
        __syncthreads();

        const bool active = (wq + 31 >= kbase);   // wave-uniform
        if (active) {
            const bool needmask = (kbase + KT - 1 > wq);

            // ---- QK^T ----
            f32x4 sf[2][4];
#pragma unroll
            for (int m2 = 0; m2 < 2; ++m2)
#pragma unroll
                for (int n = 0; n < 4; ++n) sf[m2][n] = (f32x4){0.f, 0.f, 0.f, 0.f};

#pragma unroll
            for (int n = 0; n < 4; ++n) {
                const int row = n * 16 + c;     // key row in tile
#pragma unroll
                for (int kk = 0; kk < 2; ++kk) {
                    short8 kf = *reinterpret_cast<const short8*>(
                        &Ks[(row << 6) + ((kk * 32 + g * 8) ^ ((row & 7) << 3))]);
                    sf[0][n] = __builtin_amdgcn_mfma_f32_16x16x32_bf16(qa[0][kk], kf, sf[0][n], 0, 0, 0);
                    sf[1][n] = __builtin_amdgcn_mfma_f32_16x16x32_bf16(qa[1][kk], kf, sf[1][n], 0, 0, 0);
                }
            }

            // ---- online softmax (per m2, per q-row r) ----
            float p[2][4][4];   // [m2][n][r]
#pragma unroll
            for (int m2 = 0; m2 < 2; ++m2) {
                float tm[4];
#pragma unroll
                for (int r = 0; r < 4; ++r) tm[r] = -INFINITY;
#pragma unroll
                for (int n = 0; n < 4; ++n) {
#pragma unroll
                    for (int r = 0; r < 4; ++r) {
                        float s = sf[m2][n][r] * 0.125f;
                        if (needmask) {
                            const int keyg = kbase + n * 16 + c;
                            const int qg   = wq + m2 * 16 + (g << 2) + r;
                            if (keyg > qg) s = -INFINITY;
                        }
                        p[m2][n][r] = s;
                        tm[r] = fmaxf(tm[r], s);
                    }
                }
#pragma unroll
                for (int mask = 1; mask <= 8; mask <<= 1)
#pragma unroll
                    for (int r = 0; r < 4; ++r)
                        tm[r] = fmaxf(tm[r], __shfl_xor(tm[r], mask));

                float corr[4];
#pragma unroll
                for (int r = 0; r < 4; ++r) {
                    const float mn = fmaxf(m_[m2][r], tm[r]);
                    corr[r] = __expf(m_[m2][r] - mn);   // 0 on first tile
                    m_[m2][r] = mn;
                    l_[m2][r] *= corr[r];
                }
#pragma unroll
                for (int n = 0; n < 4; ++n)
#pragma unroll
                    for (int r = 0; r < 4; ++r)
                        p[m2][n][r] = __expf(p[m2][n][r] - m_[m2][r]);

                float ls[4];
#pragma unroll
                for (int r = 0; r < 4; ++r)
                    ls[r] = ((p[m2][0][r] + p[m2][1][r]) + (p[m2][2][r] + p[m2][3][r]));
#pragma unroll
                for (int mask = 1; mask <= 8; mask <<= 1)
#pragma unroll
                    for (int r = 0; r < 4; ++r)
                        ls[r] += __shfl_xor(ls[r], mask);
#pragma unroll
                for (int r = 0; r < 4; ++r) l_[m2][r] += ls[r];

                // rescale accumulator
#pragma unroll
                for (int n = 0; n < 4; ++n)
#pragma unroll
                    for (int r = 0; r < 4; ++r)
                        o[m2][n][r] *= corr[r];
            }

            // ---- write P (bf16) to per-wave LDS ----
#pragma unroll
            for (int m2 = 0; m2 < 2; ++m2)
#pragma unroll
                for (int n = 0; n < 4; ++n)
#pragma unroll
                    for (int r = 0; r < 4; ++r) {
                        const int q2 = m2 * 16 + (g << 2) + r;   // S row
                        const int ky = n * 16 + c;               // S col (key)
                        Ps[w][(q2 << 6) + (ky ^ ((q2 & 7) << 3))] = f2bf(p[m2][n][r]);
                    }

            // ---- PV: A = P (from LDS), B = V^T ----
#pragma unroll
            for (int kk = 0; kk < 2; ++kk) {
                short8 pa0 = *reinterpret_cast<const short8*>(
                    &Ps[w][((0 * 16 + c) << 6) + ((kk * 32 + g * 8) ^ ((c & 7) << 3))]);
                short8 pa1 = *reinterpret_cast<const short8*>(
                    &Ps[w][((1 * 16 + c) << 6) + ((kk * 32 + g * 8) ^ ((c & 7) << 3))]);
#pragma unroll
                for (int n = 0; n < 4; ++n) {
                    const int d = n * 16 + c;
                    short8 vf = *reinterpret_cast<const short8*>(
                        &Vt[(d << 6) + ((kk * 32 + g * 8) ^ ((d & 7) << 3))]);
                    o[0][n] = __builtin_amdgcn_mfma_f32_16x16x32_bf16(pa0, vf, o[0][n], 0, 0, 0);
                    o[1][n] = __builtin_amdgcn_mfma_f32_16x16x32_bf16(pa1, vf, o[1][n], 0, 0, 0);
                }
            }
        } // active
    } // tiles

    // ---- epilogue: normalize and store f32 ----
#pragma unroll
    for (int m2 = 0; m2 < 2; ++m2)
#pragma unroll
        for (int r = 0; r < 4; ++r) {
            const float inv = 1.0f / l_[m2][r];
            const int q = wq + m2 * 16 + (g << 2) + r;
            float* orow = out + ((size_t)b * TN + q) * HN;
#pragma unroll
            for (int n = 0; n < 4; ++n)
                orow[n * 16 + c] = o[m2][n][r] * inv;
        }
}

// ---------------------------------------------------------------------------
extern "C" void kernel_launch(void* const* d_in, const int* in_sizes, int n_in,
                              void* d_out, int out_size, void* d_ws, size_t ws_size,
                              hipStream_t stream) {
    const float* x  = (const float*)d_in[0];
    const float* Wk = (const float*)d_in[1];
    const float* Wq = (const float*)d_in[2];
    const float* Wv = (const float*)d_in[3];
    float* out = (float*)d_out;

    // ws: q | k | vt, each B*T*H bf16 = 8.39 MB  (25.2 MB total)
    u16* qp  = (u16*)d_ws;
    u16* kp  = qp + (size_t)16 * TN * HN;
    u16* vtp = kp + (size_t)16 * TN * HN;

    qkv_proj<<<dim3(256), dim3(256), 0, stream>>>(x, Wk, Wq, Wv, qp, kp, vtp);
    attn_mfma<<<dim3(NQ, 16), dim3(256), 0, stream>>>(qp, kp, vtp, out);
}

// Round 4
// 140.940 us; speedup vs baseline: 31.8636x; 1.4617x over previous
//
#include <hip/hip_runtime.h>
#include <hip/hip_bf16.h>
#include <math.h>

typedef short short8 __attribute__((ext_vector_type(8)));
typedef float f32x4 __attribute__((ext_vector_type(4)));
typedef float f32x16 __attribute__((ext_vector_type(16)));
typedef unsigned int uint4v __attribute__((ext_vector_type(4)));
typedef unsigned short u16;

constexpr int TN = 4096;   // sequence
constexpr int CN = 32;     // embed
constexpr int HN = 64;     // head size
constexpr int QT = 128;    // q rows per block (4 waves x 32)
constexpr int KT = 64;     // keys per tile
constexpr int NQ = TN / QT; // 32 q-tiles per batch

__device__ __forceinline__ u16 f2bf(float f) {
    return __builtin_bit_cast(u16, __float2bfloat16(f));
}
__device__ __forceinline__ unsigned pack2(float lo, float hi) {
    return (unsigned)f2bf(lo) | ((unsigned)f2bf(hi) << 16);
}

// ---------------------------------------------------------------------------
// Kernel 1: fused QKV projection -> bf16.  4 threads per (b,t) row (16 h each).
// q,k row-major [b*t][64]; v transposed per batch: vt[b][h][t].
// ---------------------------------------------------------------------------
__global__ __launch_bounds__(256) void qkv_proj(
    const float* __restrict__ x,
    const float* __restrict__ Wk,
    const float* __restrict__ Wq,
    const float* __restrict__ Wv,
    u16* __restrict__ qb, u16* __restrict__ kb, u16* __restrict__ vtb)
{
    __shared__ float sW[3][CN * HN];   // 24 KB: 0=q, 1=k, 2=v

    const int tid = threadIdx.x;
#pragma unroll
    for (int i = 0; i < 8; ++i) {
        const int idx = i * 256 + tid;   // 0..2047
        sW[0][idx] = Wq[idx];
        sW[1][idx] = Wk[idx];
        sW[2][idx] = Wv[idx];
    }
    __syncthreads();

    const int gid  = blockIdx.x * 256 + tid;   // 0 .. 4*B*T-1
    const int row  = gid >> 2;                 // b*T + t
    const int qq   = gid & 3;                  // h-quarter
    const int h0   = qq * 16;
    const int b    = row >> 12;                // T = 4096
    const int tloc = row & (TN - 1);
    const float* xr = x + (size_t)row * CN;

    float xv[CN];
#pragma unroll
    for (int cc = 0; cc < CN; cc += 4) {
        f32x4 t4 = *reinterpret_cast<const f32x4*>(xr + cc);
        xv[cc] = t4[0]; xv[cc + 1] = t4[1]; xv[cc + 2] = t4[2]; xv[cc + 3] = t4[3];
    }

    float aq[16], ak[16], av[16];
#pragma unroll
    for (int j = 0; j < 16; ++j) { aq[j] = 0.f; ak[j] = 0.f; av[j] = 0.f; }

#pragma unroll
    for (int cc = 0; cc < CN; ++cc) {
        const float xc = xv[cc];
        const float* wq = &sW[0][cc * HN + h0];
        const float* wk = &sW[1][cc * HN + h0];
        const float* wv = &sW[2][cc * HN + h0];
#pragma unroll
        for (int j = 0; j < 16; ++j) {
            aq[j] += xc * wq[j];
            ak[j] += xc * wk[j];
            av[j] += xc * wv[j];
        }
    }

    u16* qo = qb + (size_t)row * HN + h0;
    u16* ko = kb + (size_t)row * HN + h0;
#pragma unroll
    for (int v8 = 0; v8 < 2; ++v8) {
        short8 pq, pk;
#pragma unroll
        for (int j = 0; j < 8; ++j) {
            pq[j] = (short)f2bf(aq[v8 * 8 + j]);
            pk[j] = (short)f2bf(ak[v8 * 8 + j]);
        }
        *reinterpret_cast<short8*>(qo + v8 * 8) = pq;
        *reinterpret_cast<short8*>(ko + v8 * 8) = pk;
    }
#pragma unroll
    for (int j = 0; j < 16; ++j)
        vtb[((size_t)b * HN + h0 + j) * TN + tloc] = f2bf(av[j]);
}

// ---------------------------------------------------------------------------
// Kernel 2: causal flash attention, 32x32x16 bf16 MFMA, in-register softmax.
//
// Wave w owns q rows [wq, wq+31].  Swapped QK^T:  S^T = K·Q^T  (A=K, B=Q)
// -> C/D col = lane&31 = q (lane-local), row = key = (reg&3)+8*(reg>>2)+4h
//    (m74/m101-verified map).
// Softmax per lane: 31 in-lane ops + __shfl_xor(,32) to combine h-halves.
// P -> bf16 B-frags assembled in-register; the 8 partner words are fetched
// with __shfl_xor(,32) (send-what-partner-needs).  A/B share the same
// per-lane element->k map, so the assembly is permutation-invariant as long
// as target element j at half h carries key 16*ks + 8*h + j  (A loaded
// linearly from LDS uses the same convention).
// PV transposed: O^T = V^T·P  -> O is q-lane-local; rescale/1/l lane-local.
// K [key][d] and V^T [d][k] LDS tiles XOR-swizzled at 16B granules:
// granule ^= (row&7)  -> all b128 accesses conflict-free.
// Epilogue: O^T -> granule-swizzled LDS f32 [128][64] -> coalesced stores.
// ---------------------------------------------------------------------------
__global__ __launch_bounds__(256, 2) void attn_mfma(
    const u16* __restrict__ qb,
    const u16* __restrict__ kb,
    const u16* __restrict__ vtb,
    float* __restrict__ out)
{
    __shared__ __align__(16) char smem[32768];
    u16* Ks = (u16*)smem;              // [64][64] bf16, swizzled      (8 KB)
    u16* Vt = (u16*)(smem + 8192);     // [64][64] bf16, swizzled      (8 KB)
    float* ep = (float*)smem;          // epilogue: [128][64] f32 swz  (32 KB)

    const int tid  = threadIdx.x;
    const int lane = tid & 63;
    const int w    = tid >> 6;
    const int c    = lane & 31;
    const int h    = lane >> 5;
    const int b    = blockIdx.y;
    // heavy/light pairing across the two dispatch halves
    const int qt    = (blockIdx.y < 8) ? (NQ - 1 - (int)blockIdx.x) : (int)blockIdx.x;
    const int qbase = qt * QT;
    const int wq    = qbase + w * 32;
    const int qg    = wq + c;          // this lane's q row

    const u16* Qg = qb  + (size_t)b * TN * HN;
    const u16* Kg = kb  + (size_t)b * TN * HN;
    const u16* Vg = vtb + (size_t)b * HN * TN;

    // Q fragments: qh[dd] = Q[qg][(2*dd+h)*8 .. +7]   (h folded into address)
    short8 qh[4];
#pragma unroll
    for (int dd = 0; dd < 4; ++dd)
        qh[dd] = *reinterpret_cast<const short8*>(
            Qg + (size_t)qg * HN + (2 * dd + h) * 8);

    f32x16 oT[2];                      // O^T acc: [dh]; col=q=c, row=d-local
#pragma unroll
    for (int dh = 0; dh < 2; ++dh)
#pragma unroll
        for (int j = 0; j < 16; ++j) oT[dh][j] = 0.f;
    float m = -INFINITY, l = 0.f;

    const int nt = 2 * qt + 2;

    // register staging: i<2 -> K granules, i>=2 -> Vt granules
    short8 stg[4];
#pragma unroll
    for (int i = 0; i < 4; ++i) {
        const int ci = i * 256 + tid;
        const int r  = (ci >> 3) & 63;
        const int g0 = ci & 7;
        stg[i] = (i < 2)
            ? *reinterpret_cast<const short8*>(Kg + (size_t)r * HN + g0 * 8)
            : *reinterpret_cast<const short8*>(Vg + (size_t)r * TN + g0 * 8);
    }

    for (int t = 0; t < nt; ++t) {
        const int kbase = t * KT;

        __syncthreads();   // previous tile fully consumed
#pragma unroll
        for (int i = 0; i < 4; ++i) {
            const int ci = i * 256 + tid;
            const int r  = (ci >> 3) & 63;
            const int g0 = ci & 7;
            u16* dst = (i < 2 ? Ks : Vt) + (r << 6) + ((g0 ^ (r & 7)) << 3);
            *reinterpret_cast<short8*>(dst) = stg[i];
        }
        __syncthreads();   // tile visible

        // issue next tile's global loads early (hide under compute)
        if (t + 1 < nt) {
            const int kn = (t + 1) * KT;
#pragma unroll
            for (int i = 0; i < 4; ++i) {
                const int ci = i * 256 + tid;
                const int r  = (ci >> 3) & 63;
                const int g0 = ci & 7;
                stg[i] = (i < 2)
                    ? *reinterpret_cast<const short8*>(Kg + (size_t)(kn + r) * HN + g0 * 8)
                    : *reinterpret_cast<const short8*>(Vg + (size_t)r * TN + kn + g0 * 8);
            }
        }

        if (wq + 31 < kbase) continue;   // wave fully masked (barriers stay uniform)

        // ---- QK^T:  S^T[key][q] ----
        f32x16 sT[2];
#pragma unroll
        for (int kb2 = 0; kb2 < 2; ++kb2) {
#pragma unroll
            for (int j = 0; j < 16; ++j) sT[kb2][j] = 0.f;
            const int row = kb2 * 32 + c;
            const int sw  = row & 7;
#pragma unroll
            for (int dd = 0; dd < 4; ++dd) {
                short8 kf = *reinterpret_cast<const short8*>(
                    &Ks[(row << 6) + (((2 * dd + h) ^ sw) << 3)]);
                sT[kb2] = __builtin_amdgcn_mfma_f32_32x32x16_bf16(
                    kf, qh[dd], sT[kb2], 0, 0, 0);
            }
        }

        // ---- softmax in log2 domain (lane owns q = qg) ----
        const bool needmask = (kbase + KT - 1 > wq);
        float p[2][16];
        float tmax = -INFINITY;
#pragma unroll
        for (int kb2 = 0; kb2 < 2; ++kb2)
#pragma unroll
            for (int r16 = 0; r16 < 16; ++r16) {
                float s = sT[kb2][r16] * 0.18033688011112042f;  // 0.125*log2(e)
                if (needmask) {
                    const int key = kbase + kb2 * 32 + (r16 & 3) + 8 * (r16 >> 2) + 4 * h;
                    if (key > qg) s = -INFINITY;
                }
                p[kb2][r16] = s;
                tmax = fmaxf(tmax, s);
            }
        tmax = fmaxf(tmax, __shfl_xor(tmax, 32));   // combine h-halves

        const float mnew = fmaxf(m, tmax);
        const float corr = exp2f(m - mnew);   // 0 on first tile
        m = mnew;

        float ts = 0.f;
#pragma unroll
        for (int kb2 = 0; kb2 < 2; ++kb2)
#pragma unroll
            for (int r16 = 0; r16 < 16; ++r16) {
                const float e = exp2f(p[kb2][r16] - mnew);
                p[kb2][r16] = e;
                ts += e;
            }
        ts += __shfl_xor(ts, 32);
        l = l * corr + ts;

#pragma unroll
        for (int dh = 0; dh < 2; ++dh)
#pragma unroll
            for (int j = 0; j < 16; ++j) oT[dh][j] *= corr;

        // ---- P -> bf16 B-frags + PV ----
        // own packed words: wpk[kb2][i] = (p[2i], p[2i+1]) -> keys
        //   8*(i>>1) + 2*(i&1) + 4h  and +1   (within 32-block kb2)
        unsigned wpk[2][8];
#pragma unroll
        for (int kb2 = 0; kb2 < 2; ++kb2)
#pragma unroll
            for (int i = 0; i < 8; ++i)
                wpk[kb2][i] = pack2(p[kb2][2 * i], p[kb2][2 * i + 1]);

        // fetch partner words (send what the partner needs):
        // h=0 receives partner's {i0,i1,i4,i5}; h=1 receives partner's {i2,i3,i6,i7}
        unsigned rx[2][4];
#pragma unroll
        for (int kb2 = 0; kb2 < 2; ++kb2) {
            rx[kb2][0] = __shfl_xor(h ? wpk[kb2][0] : wpk[kb2][2], 32);
            rx[kb2][1] = __shfl_xor(h ? wpk[kb2][1] : wpk[kb2][3], 32);
            rx[kb2][2] = __shfl_xor(h ? wpk[kb2][4] : wpk[kb2][6], 32);
            rx[kb2][3] = __shfl_xor(h ? wpk[kb2][5] : wpk[kb2][7], 32);
        }

#pragma unroll
        for (int ks = 0; ks < 4; ++ks) {
            const int kb2 = ks >> 1;
            const int s2  = ks & 1;
            // target: element j at half h = P[key 16*ks + 8*h + j][q=c]
            uint4v uw;
            uw.x = h ? rx[kb2][2 * s2 + 0] : wpk[kb2][4 * s2 + 0];
            uw.y = h ? rx[kb2][2 * s2 + 1] : wpk[kb2][4 * s2 + 1];
            uw.z = h ? wpk[kb2][4 * s2 + 2] : rx[kb2][2 * s2 + 0];
            uw.w = h ? wpk[kb2][4 * s2 + 3] : rx[kb2][2 * s2 + 1];
            short8 pa = __builtin_bit_cast(short8, uw);
#pragma unroll
            for (int dh = 0; dh < 2; ++dh) {
                const int row = dh * 32 + c;
                short8 vf = *reinterpret_cast<const short8*>(
                    &Vt[(row << 6) + (((2 * ks + h) ^ (row & 7)) << 3)]);
                oT[dh] = __builtin_amdgcn_mfma_f32_32x32x16_bf16(
                    vf, pa, oT[dh], 0, 0, 0);
            }
        }
    }

    // ---- epilogue: normalize, transpose via swizzled LDS, coalesced store ----
    __syncthreads();   // all waves done with Ks/Vt
    const float inv = 1.0f / l;
    const int q_loc = 32 * w + c;
#pragma unroll
    for (int dh = 0; dh < 2; ++dh)
#pragma unroll
        for (int tq = 0; tq < 4; ++tq) {
            const int d0   = 32 * dh + 8 * tq + 4 * h;      // regs 4tq..4tq+3
            const int gidx = (d0 >> 2) ^ (q_loc & 7);
            f32x4 vv;
            vv[0] = oT[dh][4 * tq + 0] * inv;
            vv[1] = oT[dh][4 * tq + 1] * inv;
            vv[2] = oT[dh][4 * tq + 2] * inv;
            vv[3] = oT[dh][4 * tq + 3] * inv;
            *reinterpret_cast<f32x4*>(&ep[(q_loc << 6) + (gidx << 2)]) = vv;
        }
    __syncthreads();
    {
        const int r = tid >> 1, half = tid & 1;
        float* orow = out + ((size_t)b * TN + qbase + r) * HN + half * 32;
#pragma unroll
        for (int i = 0; i < 8; ++i) {
            const int g = (8 * half + i) ^ (r & 7);
            f32x4 vv = *reinterpret_cast<const f32x4*>(&ep[(r << 6) + (g << 2)]);
            *reinterpret_cast<f32x4*>(&orow[i * 4]) = vv;
        }
    }
}

// ---------------------------------------------------------------------------
extern "C" void kernel_launch(void* const* d_in, const int* in_sizes, int n_in,
                              void* d_out, int out_size, void* d_ws, size_t ws_size,
                              hipStream_t stream) {
    const float* x  = (const float*)d_in[0];
    const float* Wk = (const float*)d_in[1];
    const float* Wq = (const float*)d_in[2];
    const float* Wv = (const float*)d_in[3];
    float* out = (float*)d_out;

    // ws: q | k | vt, each B*T*H bf16 = 8.39 MB  (25.2 MB total)
    u16* qp  = (u16*)d_ws;
    u16* kp  = qp + (size_t)16 * TN * HN;
    u16* vtp = kp + (size_t)16 * TN * HN;

    qkv_proj<<<dim3(1024), dim3(256), 0, stream>>>(x, Wk, Wq, Wv, qp, kp, vtp);
    attn_mfma<<<dim3(NQ, 16), dim3(256), 0, stream>>>(qp, kp, vtp, out);
}

// Round 5
// 129.082 us; speedup vs baseline: 34.7906x; 1.0919x over previous
//
#include <hip/hip_runtime.h>
#include <hip/hip_bf16.h>
#include <math.h>

typedef short short8 __attribute__((ext_vector_type(8)));
typedef float f32x4 __attribute__((ext_vector_type(4)));
typedef float f32x16 __attribute__((ext_vector_type(16)));
typedef unsigned int uint4v __attribute__((ext_vector_type(4)));
typedef unsigned short u16;

constexpr int TN = 4096;    // sequence
constexpr int CN = 32;      // embed
constexpr int HN = 64;      // head size
constexpr int QT = 128;     // q rows per block (4 waves x 32)
constexpr int KT = 64;      // keys per tile
constexpr int NQ = TN / QT; // 32 q-tiles per batch
constexpr int BN = 16;      // batch
constexpr size_t BT  = (size_t)BN * TN;
constexpr size_t BTH = BT * (size_t)HN;
constexpr float SCL = 0.18033688011112042f;  // 0.125 * log2(e), folded into q

__device__ __forceinline__ u16 f2bf(float f) {
    return __builtin_bit_cast(u16, __float2bfloat16(f));
}
__device__ __forceinline__ float bf2f(u16 v) {
    return __builtin_bit_cast(float, (unsigned)v << 16);
}
__device__ __forceinline__ unsigned pack2(float lo, float hi) {
    return (unsigned)f2bf(lo) | ((unsigned)f2bf(hi) << 16);
}

// ---------------------------------------------------------------------------
// Kernel 1: fused QKV projection -> bf16.  4 threads per (b,t) row (16 h each).
// q is PRE-SCALED by 0.125*log2(e) (softmax runs in log2 domain, scale-free).
// q,k row-major [b*t][64]; v transposed per batch: vt[b][h][t].
// ---------------------------------------------------------------------------
__global__ __launch_bounds__(256) void qkv_proj(
    const float* __restrict__ x,
    const float* __restrict__ Wk,
    const float* __restrict__ Wq,
    const float* __restrict__ Wv,
    u16* __restrict__ qb, u16* __restrict__ kb, u16* __restrict__ vtb)
{
    __shared__ float sW[3][CN * HN];   // 24 KB: 0=q, 1=k, 2=v

    const int tid = threadIdx.x;
#pragma unroll
    for (int i = 0; i < 8; ++i) {
        const int idx = i * 256 + tid;   // 0..2047
        sW[0][idx] = Wq[idx];
        sW[1][idx] = Wk[idx];
        sW[2][idx] = Wv[idx];
    }
    __syncthreads();

    const int gid  = blockIdx.x * 256 + tid;   // 0 .. 4*B*T-1
    const int row  = gid >> 2;                 // b*T + t
    const int qq   = gid & 3;                  // h-quarter
    const int h0   = qq * 16;
    const int b    = row >> 12;                // T = 4096
    const int tloc = row & (TN - 1);
    const float* xr = x + (size_t)row * CN;

    float xv[CN];
#pragma unroll
    for (int cc = 0; cc < CN; cc += 4) {
        f32x4 t4 = *reinterpret_cast<const f32x4*>(xr + cc);
        xv[cc] = t4[0]; xv[cc + 1] = t4[1]; xv[cc + 2] = t4[2]; xv[cc + 3] = t4[3];
    }

    float aq[16], ak[16], av[16];
#pragma unroll
    for (int j = 0; j < 16; ++j) { aq[j] = 0.f; ak[j] = 0.f; av[j] = 0.f; }

#pragma unroll
    for (int cc = 0; cc < CN; ++cc) {
        const float xc = xv[cc];
        const float* wq = &sW[0][cc * HN + h0];
        const float* wk = &sW[1][cc * HN + h0];
        const float* wv = &sW[2][cc * HN + h0];
#pragma unroll
        for (int j = 0; j < 16; ++j) {
            aq[j] += xc * wq[j];
            ak[j] += xc * wk[j];
            av[j] += xc * wv[j];
        }
    }

    u16* qo = qb + (size_t)row * HN + h0;
    u16* ko = kb + (size_t)row * HN + h0;
#pragma unroll
    for (int v8 = 0; v8 < 2; ++v8) {
        short8 pq, pk;
#pragma unroll
        for (int j = 0; j < 8; ++j) {
            pq[j] = (short)f2bf(aq[v8 * 8 + j] * SCL);   // fold softmax scale
            pk[j] = (short)f2bf(ak[v8 * 8 + j]);
        }
        *reinterpret_cast<short8*>(qo + v8 * 8) = pq;
        *reinterpret_cast<short8*>(ko + v8 * 8) = pk;
    }
#pragma unroll
    for (int j = 0; j < 16; ++j)
        vtb[((size_t)b * HN + h0 + j) * TN + tloc] = f2bf(av[j]);
}

// ---------------------------------------------------------------------------
// Kernel 2: causal flash attention, 32x32x16 bf16 MFMA, in-register softmax,
// 2-way K-SPLIT: block (bx,by,z) processes key-tiles t ≡ z (mod 2) and writes
// an l-normalized partial O (bf16) + lse = m + log2(l) per q row.
//
// Same verified structure as R4: swapped QK^T (S^T = K·Q^T, q lane-local,
// m74/m101 C/D map), lane-local log2-domain softmax with one __shfl_xor(,32)
// per reduce, in-register P->bf16 B-frag assembly (send-what-partner-needs),
// transposed PV (O^T = V^T·P), 16B-granule XOR-swizzled K/V^T LDS tiles,
// granule-swizzled f32 LDS epilogue transpose.
// New: T13 defer-rescale (skip corr when all lanes' tmax-m <= 8 in log2).
// ---------------------------------------------------------------------------
__global__ __launch_bounds__(256, 4) void attn_mfma(
    const u16* __restrict__ qb,
    const u16* __restrict__ kb,
    const u16* __restrict__ vtb,
    u16* __restrict__ pO,
    float* __restrict__ lseb)
{
    __shared__ __align__(16) char smem[32768];
    u16* Ks = (u16*)smem;              // [64][64] bf16, swizzled      (8 KB)
    u16* Vt = (u16*)(smem + 8192);     // [64][64] bf16, swizzled      (8 KB)
    float* ep = (float*)smem;          // epilogue: [128][64] f32 swz  (32 KB)

    const int tid  = threadIdx.x;
    const int lane = tid & 63;
    const int w    = tid >> 6;
    const int c    = lane & 31;
    const int h    = lane >> 5;
    const int b    = blockIdx.y;
    const int par  = blockIdx.z;       // key-tile parity
    // heavy/light pairing across the two by-halves
    const int qt    = (blockIdx.y < 8) ? (NQ - 1 - (int)blockIdx.x) : (int)blockIdx.x;
    const int qbase = qt * QT;
    const int wq    = qbase + w * 32;
    const int qg    = wq + c;          // this lane's q row

    const u16* Qg = qb  + (size_t)b * TN * HN;
    const u16* Kg = kb  + (size_t)b * TN * HN;
    const u16* Vg = vtb + (size_t)b * HN * TN;

    // Q fragments: qh[dd] = Q[qg][(2*dd+h)*8 .. +7]   (h folded into address)
    short8 qh[4];
#pragma unroll
    for (int dd = 0; dd < 4; ++dd)
        qh[dd] = *reinterpret_cast<const short8*>(
            Qg + (size_t)qg * HN + (2 * dd + h) * 8);

    f32x16 oT[2];                      // O^T acc: [dh]; col=q=c, row=d-local
#pragma unroll
    for (int dh = 0; dh < 2; ++dh)
#pragma unroll
        for (int j = 0; j < 16; ++j) oT[dh][j] = 0.f;
    float m = -INFINITY, l = 0.f;

    const int nt = 2 * qt + 2;

    // register staging for tile `par`: i<2 -> K granules, i>=2 -> Vt granules
    short8 stg[4];
#pragma unroll
    for (int i = 0; i < 4; ++i) {
        const int ci = i * 256 + tid;
        const int r  = (ci >> 3) & 63;
        const int g0 = ci & 7;
        stg[i] = (i < 2)
            ? *reinterpret_cast<const short8*>(Kg + (size_t)(par * KT + r) * HN + g0 * 8)
            : *reinterpret_cast<const short8*>(Vg + (size_t)r * TN + par * KT + g0 * 8);
    }

    for (int t = par; t < nt; t += 2) {
        const int kbase = t * KT;

        __syncthreads();   // previous tile fully consumed
#pragma unroll
        for (int i = 0; i < 4; ++i) {
            const int ci = i * 256 + tid;
            const int r  = (ci >> 3) & 63;
            const int g0 = ci & 7;
            u16* dst = (i < 2 ? Ks : Vt) + (r << 6) + ((g0 ^ (r & 7)) << 3);
            *reinterpret_cast<short8*>(dst) = stg[i];
        }
        __syncthreads();   // tile visible

        // issue next parity-tile's global loads early (hide under compute)
        if (t + 2 < nt) {
            const int kn = (t + 2) * KT;
#pragma unroll
            for (int i = 0; i < 4; ++i) {
                const int ci = i * 256 + tid;
                const int r  = (ci >> 3) & 63;
                const int g0 = ci & 7;
                stg[i] = (i < 2)
                    ? *reinterpret_cast<const short8*>(Kg + (size_t)(kn + r) * HN + g0 * 8)
                    : *reinterpret_cast<const short8*>(Vg + (size_t)r * TN + kn + g0 * 8);
            }
        }

        if (wq + 31 < kbase) continue;   // wave fully masked (barriers stay uniform)

        // ---- QK^T:  S^T[key][q]  (scores pre-scaled via q) ----
        f32x16 sT[2];
#pragma unroll
        for (int kb2 = 0; kb2 < 2; ++kb2) {
#pragma unroll
            for (int j = 0; j < 16; ++j) sT[kb2][j] = 0.f;
            const int row = kb2 * 32 + c;
            const int sw  = row & 7;
#pragma unroll
            for (int dd = 0; dd < 4; ++dd) {
                short8 kf = *reinterpret_cast<const short8*>(
                    &Ks[(row << 6) + (((2 * dd + h) ^ sw) << 3)]);
                sT[kb2] = __builtin_amdgcn_mfma_f32_32x32x16_bf16(
                    kf, qh[dd], sT[kb2], 0, 0, 0);
            }
        }

        // ---- log2-domain online softmax (lane owns q = qg) ----
        const bool needmask = (kbase + KT - 1 > wq);
        float p[2][16];
        float tmax = -INFINITY;
#pragma unroll
        for (int kb2 = 0; kb2 < 2; ++kb2)
#pragma unroll
            for (int r16 = 0; r16 < 16; ++r16) {
                float s = sT[kb2][r16];
                if (needmask) {
                    const int key = kbase + kb2 * 32 + (r16 & 3) + 8 * (r16 >> 2) + 4 * h;
                    if (key > qg) s = -INFINITY;
                }
                p[kb2][r16] = s;
                tmax = fmaxf(tmax, s);
            }
        tmax = fmaxf(tmax, __shfl_xor(tmax, 32));   // combine h-halves

        // T13 defer-rescale: only rescale when some lane's max grew by >8
        if (!__all(tmax - m <= 8.0f)) {
            const float mnew = fmaxf(fmaxf(m, tmax), -1e30f);  // clamp: no -inf m
            const float corr = exp2f(m - mnew);                // 0 on first tile
            l *= corr;
            m = mnew;
#pragma unroll
            for (int dh = 0; dh < 2; ++dh)
#pragma unroll
                for (int j = 0; j < 16; ++j) oT[dh][j] *= corr;
        }

        float ts = 0.f;
#pragma unroll
        for (int kb2 = 0; kb2 < 2; ++kb2)
#pragma unroll
            for (int r16 = 0; r16 < 16; ++r16) {
                const float e = exp2f(p[kb2][r16] - m);   // bounded by 2^8
                p[kb2][r16] = e;
                ts += e;
            }
        ts += __shfl_xor(ts, 32);
        l += ts;

        // ---- P -> bf16 B-frags + PV ----
        unsigned wpk[2][8];
#pragma unroll
        for (int kb2 = 0; kb2 < 2; ++kb2)
#pragma unroll
            for (int i = 0; i < 8; ++i)
                wpk[kb2][i] = pack2(p[kb2][2 * i], p[kb2][2 * i + 1]);

        // partner words via __shfl_xor(,32) (send what the partner needs)
        unsigned rx[2][4];
#pragma unroll
        for (int kb2 = 0; kb2 < 2; ++kb2) {
            rx[kb2][0] = __shfl_xor(h ? wpk[kb2][0] : wpk[kb2][2], 32);
            rx[kb2][1] = __shfl_xor(h ? wpk[kb2][1] : wpk[kb2][3], 32);
            rx[kb2][2] = __shfl_xor(h ? wpk[kb2][4] : wpk[kb2][6], 32);
            rx[kb2][3] = __shfl_xor(h ? wpk[kb2][5] : wpk[kb2][7], 32);
        }

#pragma unroll
        for (int ks = 0; ks < 4; ++ks) {
            const int kb2 = ks >> 1;
            const int s2  = ks & 1;
            // element j at half h = P[key 16*ks + 8*h + j][q=c]
            uint4v uw;
            uw.x = h ? rx[kb2][2 * s2 + 0] : wpk[kb2][4 * s2 + 0];
            uw.y = h ? rx[kb2][2 * s2 + 1] : wpk[kb2][4 * s2 + 1];
            uw.z = h ? wpk[kb2][4 * s2 + 2] : rx[kb2][2 * s2 + 0];
            uw.w = h ? wpk[kb2][4 * s2 + 3] : rx[kb2][2 * s2 + 1];
            short8 pa = __builtin_bit_cast(short8, uw);
#pragma unroll
            for (int dh = 0; dh < 2; ++dh) {
                const int row = dh * 32 + c;
                short8 vf = *reinterpret_cast<const short8*>(
                    &Vt[(row << 6) + (((2 * ks + h) ^ (row & 7)) << 3)]);
                oT[dh] = __builtin_amdgcn_mfma_f32_32x32x16_bf16(
                    vf, pa, oT[dh], 0, 0, 0);
            }
        }
    }

    // ---- epilogue: normalize partial, transpose via swizzled LDS, store ----
    __syncthreads();   // all waves done with Ks/Vt
    const float inv  = (l > 0.f) ? (1.0f / l) : 0.f;
    const float lseV = (l > 0.f) ? (m + log2f(l)) : -INFINITY;
    if (h == 0)
        lseb[(size_t)par * BT + (size_t)b * TN + qg] = lseV;

    const int q_loc = 32 * w + c;
#pragma unroll
    for (int dh = 0; dh < 2; ++dh)
#pragma unroll
        for (int tq = 0; tq < 4; ++tq) {
            const int d0   = 32 * dh + 8 * tq + 4 * h;      // regs 4tq..4tq+3
            const int gidx = (d0 >> 2) ^ (q_loc & 7);
            f32x4 vv;
            vv[0] = oT[dh][4 * tq + 0] * inv;
            vv[1] = oT[dh][4 * tq + 1] * inv;
            vv[2] = oT[dh][4 * tq + 2] * inv;
            vv[3] = oT[dh][4 * tq + 3] * inv;
            *reinterpret_cast<f32x4*>(&ep[(q_loc << 6) + (gidx << 2)]) = vv;
        }
    __syncthreads();
    {
        const int r = tid >> 1, half = tid & 1;
        u16* prow = pO + (size_t)par * BTH
                       + ((size_t)b * TN + qbase + r) * HN + half * 32;
        short8 sv[4];
#pragma unroll
        for (int i = 0; i < 8; ++i) {
            const int g = (8 * half + i) ^ (r & 7);
            f32x4 vv = *reinterpret_cast<const f32x4*>(&ep[(r << 6) + (g << 2)]);
#pragma unroll
            for (int j = 0; j < 4; ++j)
                sv[i >> 1][(i & 1) * 4 + j] = (short)f2bf(vv[j]);
        }
#pragma unroll
        for (int i8 = 0; i8 < 4; ++i8)
            *reinterpret_cast<short8*>(prow + i8 * 8) = sv[i8];
    }
}

// ---------------------------------------------------------------------------
// Kernel 3: merge the two K-split partials.
// out[row,d] = (w0*O0 + w1*O1),  w_i = 2^(lse_i - M) / sum  (lse = m+log2 l).
// 8 threads per row, 8 d each.
// ---------------------------------------------------------------------------
__global__ __launch_bounds__(256) void merge_k(
    const u16* __restrict__ pO,
    const float* __restrict__ lseb,
    float* __restrict__ out)
{
    const int gid = blockIdx.x * 256 + threadIdx.x;   // 0 .. 8*B*T-1
    const int row = gid >> 3;
    const int d0  = (gid & 7) * 8;

    const float l0 = lseb[row];
    const float l1 = lseb[BT + row];
    const float M  = fmaxf(l0, l1);
    float w0 = exp2f(l0 - M);
    float w1 = exp2f(l1 - M);
    const float rden = 1.0f / (w0 + w1);
    w0 *= rden; w1 *= rden;

    short8 a = *reinterpret_cast<const short8*>(pO + (size_t)row * HN + d0);
    short8 bb = *reinterpret_cast<const short8*>(pO + BTH + (size_t)row * HN + d0);

    f32x4 o0, o1;
#pragma unroll
    for (int j = 0; j < 4; ++j)
        o0[j] = w0 * bf2f((u16)a[j]) + w1 * bf2f((u16)bb[j]);
#pragma unroll
    for (int j = 0; j < 4; ++j)
        o1[j] = w0 * bf2f((u16)a[4 + j]) + w1 * bf2f((u16)bb[4 + j]);

    float* orow = out + (size_t)row * HN + d0;
    *reinterpret_cast<f32x4*>(orow)     = o0;
    *reinterpret_cast<f32x4*>(orow + 4) = o1;
}

// ---------------------------------------------------------------------------
extern "C" void kernel_launch(void* const* d_in, const int* in_sizes, int n_in,
                              void* d_out, int out_size, void* d_ws, size_t ws_size,
                              hipStream_t stream) {
    const float* x  = (const float*)d_in[0];
    const float* Wk = (const float*)d_in[1];
    const float* Wq = (const float*)d_in[2];
    const float* Wv = (const float*)d_in[3];
    float* out = (float*)d_out;

    // ws: q | k | vt (bf16, BTH each) | pO (bf16, 2*BTH) | lse (f32, 2*BT)
    //   = 5*8.39 MB + 0.52 MB ≈ 42.5 MB
    u16* qp   = (u16*)d_ws;
    u16* kp   = qp + BTH;
    u16* vtp  = kp + BTH;
    u16* pO   = vtp + BTH;
    float* lseb = (float*)(pO + 2 * BTH);

    qkv_proj<<<dim3(1024), dim3(256), 0, stream>>>(x, Wk, Wq, Wv, qp, kp, vtp);
    attn_mfma<<<dim3(NQ, 16, 2), dim3(256), 0, stream>>>(qp, kp, vtp, pO, lseb);
    merge_k<<<dim3(8 * BT / 256), dim3(256), 0, stream>>>(pO, lseb, out);
}